// Round 1
// baseline (1070.111 us; speedup 1.0000x reference)
//
#include <hip/hip_runtime.h>
#include <math.h>

#define BN 4
#define CIN 128
#define HH 32
#define WW 32
#define HWP 1024
#define NHEAD 8

// ---------------- K1: 3x3 convs (conv_out 256ch + qkv 768ch) ----------------
// grid (32 co-tiles, 32 y, 4 b), block 256 = 32 co x 8 x-slots (4 x each)
__global__ __launch_bounds__(256) void conv3x3_kernel(
    const float* __restrict__ x,
    const float* __restrict__ conv_w, const float* __restrict__ conv_b,
    const float* __restrict__ qkv_w, const float* __restrict__ qkv_b,
    float* __restrict__ out,
    float* __restrict__ qbuf, float* __restrict__ kbuf, float* __restrict__ vbuf)
{
    __shared__ float xs[CIN][3][34];   // 52224 B
    const int tid = threadIdx.x;
    const int cotile = blockIdx.x;
    const int y = blockIdx.y;
    const int b = blockIdx.z;

    for (int idx = tid; idx < CIN * 3 * 34; idx += 256) {
        int ci = idx / 102;
        int rem = idx - ci * 102;
        int ky = rem / 34;
        int xc = rem - ky * 34;
        int gy = y + ky - 1;
        int gx = xc - 1;
        float v = 0.f;
        if ((unsigned)gy < 32u && (unsigned)gx < 32u)
            v = x[((b * CIN + ci) * HH + gy) * WW + gx];
        xs[ci][ky][xc] = v;
    }
    __syncthreads();

    const int co_local = tid >> 3;
    const int x0 = (tid & 7) * 4;
    const int co = cotile * 32 + co_local;

    const float* wbase;
    float bias;
    if (co < 256) { wbase = conv_w + co * 1152; bias = conv_b[co]; }
    else         { int c2 = co - 256; wbase = qkv_w + c2 * 1152; bias = qkv_b[c2]; }

    float acc0 = 0.f, acc1 = 0.f, acc2 = 0.f, acc3 = 0.f;
    for (int ci = 0; ci < CIN; ++ci) {
        const float* wp = wbase + ci * 9;
        float w00 = wp[0], w01 = wp[1], w02 = wp[2];
        float w10 = wp[3], w11 = wp[4], w12 = wp[5];
        float w20 = wp[6], w21 = wp[7], w22 = wp[8];

        const float* r0 = &xs[ci][0][x0];
        float a0 = r0[0], a1 = r0[1], a2 = r0[2], a3 = r0[3], a4 = r0[4], a5 = r0[5];
        acc0 += w00 * a0 + w01 * a1 + w02 * a2;
        acc1 += w00 * a1 + w01 * a2 + w02 * a3;
        acc2 += w00 * a2 + w01 * a3 + w02 * a4;
        acc3 += w00 * a3 + w01 * a4 + w02 * a5;

        const float* r1 = &xs[ci][1][x0];
        a0 = r1[0]; a1 = r1[1]; a2 = r1[2]; a3 = r1[3]; a4 = r1[4]; a5 = r1[5];
        acc0 += w10 * a0 + w11 * a1 + w12 * a2;
        acc1 += w10 * a1 + w11 * a2 + w12 * a3;
        acc2 += w10 * a2 + w11 * a3 + w12 * a4;
        acc3 += w10 * a3 + w11 * a4 + w12 * a5;

        const float* r2 = &xs[ci][2][x0];
        a0 = r2[0]; a1 = r2[1]; a2 = r2[2]; a3 = r2[3]; a4 = r2[4]; a5 = r2[5];
        acc0 += w20 * a0 + w21 * a1 + w22 * a2;
        acc1 += w20 * a1 + w21 * a2 + w22 * a3;
        acc2 += w20 * a2 + w21 * a3 + w22 * a4;
        acc3 += w20 * a3 + w21 * a4 + w22 * a5;
    }

    float vals[4] = { acc0 + bias, acc1 + bias, acc2 + bias, acc3 + bias };

    if (co < 256) {
        float* op = out + ((size_t)(b * 512 + co) * HWP) + y * WW + x0;
        op[0] = vals[0]; op[1] = vals[1]; op[2] = vals[2]; op[3] = vals[3];
    } else {
        int c2 = co - 256;
        int which = c2 >> 8;       // 0=q,1=k,2=v
        int cc = c2 & 255;
        int h = cc >> 5, d = cc & 31;
        float scale = (which == 0) ? 0.17677669529663687f : 1.0f;
        float* buf = (which == 0) ? qbuf : ((which == 1) ? kbuf : vbuf);
        size_t base = ((size_t)(b * NHEAD + h) * HWP + y * WW + x0) * 32 + d;
        buf[base + 0 * 32] = vals[0] * scale;
        buf[base + 1 * 32] = vals[1] * scale;
        buf[base + 2 * 32] = vals[2] * scale;
        buf[base + 3 * 32] = vals[3] * scale;
    }
}

// ---------------- K2: relative logit row-vectors Rx, Ry ----------------
// Rx[bh,i,x2] = q[bh, i]        . kr_x[x2 - x_i + 31]
// Ry[bh,i,y2] = q[bh, xi*32+yi] . kr_y[y2 - x_i + 31]
__global__ __launch_bounds__(256) void rel_kernel(
    const float* __restrict__ qbuf,
    const float* __restrict__ kr_x, const float* __restrict__ kr_y,
    float* __restrict__ rx, float* __restrict__ ry)
{
    int g = blockIdx.x * 256 + threadIdx.x;   // 32 bh * 1024 i * 64 m
    int m = g & 63;
    int i = (g >> 6) & 1023;
    int bh = g >> 16;
    int yi = i >> 5, xi = i & 31;

    const float* qrow;
    const float* kr;
    float* dst;
    if (m < 32) {
        qrow = qbuf + ((size_t)bh * HWP + i) * 32;
        kr = kr_x + (m - xi + 31) * 32;
        dst = rx + ((size_t)bh * HWP + i) * 32 + m;
    } else {
        int y2 = m - 32;
        qrow = qbuf + ((size_t)bh * HWP + (xi * 32 + yi)) * 32;
        kr = kr_y + (y2 - xi + 31) * 32;
        dst = ry + ((size_t)bh * HWP + i) * 32 + y2;
    }
    float s = 0.f;
#pragma unroll
    for (int d = 0; d < 32; d += 4) {
        float4 a = *(const float4*)(qrow + d);
        float4 c = *(const float4*)(kr + d);
        s += a.x * c.x + a.y * c.y + a.z * c.z + a.w * c.w;
    }
    *dst = s;
}

// ---------------- K3: flash attention per (b,h) ----------------
// grid (32 i-blocks, 32 bh), block 256 = 32 rows x 8 lanes/row
__global__ __launch_bounds__(256) void attn_kernel(
    const float* __restrict__ qbuf, const float* __restrict__ kbuf,
    const float* __restrict__ vbuf,
    const float* __restrict__ rx, const float* __restrict__ ry,
    float* __restrict__ attc)
{
    __shared__ float Qs[32][33], Rxs[32][33], Rys[32][33];
    __shared__ float Ks[128][33], Vs[128][33];
    const int tid = threadIdx.x;
    const int ib = blockIdx.x;
    const int bh = blockIdx.y;
    const int il = tid >> 3, jl = tid & 7;

    for (int idx = tid; idx < 32 * 32; idx += 256) {
        int r = idx >> 5, c = idx & 31;
        size_t base = ((size_t)bh * HWP + ib * 32 + r) * 32 + c;
        Qs[r][c] = qbuf[base];
        Rxs[r][c] = rx[base];
        Rys[r][c] = ry[base];
    }

    float mrun = -INFINITY, lrun = 0.f;
    float acc[32];
#pragma unroll
    for (int d = 0; d < 32; ++d) acc[d] = 0.f;

    for (int jt = 0; jt < 8; ++jt) {
        __syncthreads();
        for (int idx = tid; idx < 128 * 32; idx += 256) {
            int r = idx >> 5, c = idx & 31;
            size_t base = ((size_t)bh * HWP + jt * 128 + r) * 32 + c;
            Ks[r][c] = kbuf[base];
            Vs[r][c] = vbuf[base];
        }
        __syncthreads();

        float s[16];
#pragma unroll
        for (int k = 0; k < 16; ++k) {
            int jloc = jl + k * 8;
            float sc = 0.f;
#pragma unroll
            for (int d = 0; d < 32; ++d)
                sc += Qs[il][d] * Ks[jloc][d];
            int xj = jloc & 31;
            int yj = jt * 4 + (jloc >> 5);
            s[k] = sc + Rxs[il][xj] + Rys[il][yj];
        }

        float tmax = s[0];
#pragma unroll
        for (int k = 1; k < 16; ++k) tmax = fmaxf(tmax, s[k]);
        tmax = fmaxf(tmax, __shfl_xor(tmax, 1));
        tmax = fmaxf(tmax, __shfl_xor(tmax, 2));
        tmax = fmaxf(tmax, __shfl_xor(tmax, 4));

        float newm = fmaxf(mrun, tmax);
        float alpha = __expf(mrun - newm);
        float tsum = 0.f;
#pragma unroll
        for (int k = 0; k < 16; ++k) { s[k] = __expf(s[k] - newm); tsum += s[k]; }
        tsum += __shfl_xor(tsum, 1);
        tsum += __shfl_xor(tsum, 2);
        tsum += __shfl_xor(tsum, 4);
        lrun = lrun * alpha + tsum;
        mrun = newm;

#pragma unroll
        for (int d = 0; d < 32; ++d) acc[d] *= alpha;
#pragma unroll
        for (int k = 0; k < 16; ++k) {
            int jloc = jl + k * 8;
            float p = s[k];
#pragma unroll
            for (int d = 0; d < 32; ++d)
                acc[d] += p * Vs[jloc][d];
        }
    }

    // combine partial O across the 8 lanes of each row
#pragma unroll
    for (int off = 1; off < 8; off <<= 1) {
#pragma unroll
        for (int d = 0; d < 32; ++d)
            acc[d] += __shfl_xor(acc[d], off);
    }

    float inv = 1.0f / lrun;
    int b = bh >> 3, h = bh & 7;
    int yi = ib, xi = il;
    // bug-faithful scramble: channel h*32+y_i, pixel (y=x_i, x=d)
    float* op = attc + ((size_t)(b * 256 + h * 32 + yi) * 32 + xi) * 32;
#pragma unroll
    for (int u = 0; u < 4; ++u) {
        int d = jl + 8 * u;
        op[d] = acc[d] * inv;
    }
}

// ---------------- K4: 1x1 conv (256 -> 256) on scrambled att ----------------
// grid (32 y, 4 b), block 256 = 8 o-groups x 32 x
__global__ __launch_bounds__(256) void conv1x1_kernel(
    const float* __restrict__ attc,
    const float* __restrict__ att_w, const float* __restrict__ att_b,
    float* __restrict__ out)
{
    __shared__ float ins[256][33];  // 33792 B
    const int tid = threadIdx.x;
    const int y = blockIdx.x;
    const int b = blockIdx.y;

    for (int idx = tid; idx < 256 * 32; idx += 256) {
        int c = idx >> 5, xx = idx & 31;
        ins[c][xx] = attc[((size_t)(b * 256 + c) * 32 + y) * 32 + xx];
    }
    __syncthreads();

    const int xx = tid & 31;
    const int og = tid >> 5;
    float acc[32];
#pragma unroll
    for (int oo = 0; oo < 32; ++oo) acc[oo] = att_b[og * 32 + oo];

    for (int c = 0; c < 256; ++c) {
        float iv = ins[c][xx];
        const float* wp = att_w + (size_t)(og * 32) * 256 + c;
#pragma unroll
        for (int oo = 0; oo < 32; ++oo)
            acc[oo] += wp[(size_t)oo * 256] * iv;
    }

#pragma unroll
    for (int oo = 0; oo < 32; ++oo) {
        int o = og * 32 + oo;
        out[((size_t)(b * 512 + 256 + o) * HWP) + y * 32 + xx] = acc[oo];
    }
}

extern "C" void kernel_launch(void* const* d_in, const int* in_sizes, int n_in,
                              void* d_out, int out_size, void* d_ws, size_t ws_size,
                              hipStream_t stream) {
    const float* x      = (const float*)d_in[0];
    const float* conv_w = (const float*)d_in[1];
    const float* conv_b = (const float*)d_in[2];
    const float* qkv_w  = (const float*)d_in[3];
    const float* qkv_b  = (const float*)d_in[4];
    const float* att_w  = (const float*)d_in[5];
    const float* att_b  = (const float*)d_in[6];
    const float* kr_x   = (const float*)d_in[7];
    const float* kr_y   = (const float*)d_in[8];
    float* out = (float*)d_out;

    float* ws = (float*)d_ws;
    const size_t M = 1u << 20;   // 1M floats = 4 MB per buffer
    float* qbuf = ws + 0 * M;
    float* kbuf = ws + 1 * M;
    float* vbuf = ws + 2 * M;
    float* rxb  = ws + 3 * M;
    float* ryb  = ws + 4 * M;
    float* attc = ws + 5 * M;

    conv3x3_kernel<<<dim3(32, 32, 4), 256, 0, stream>>>(
        x, conv_w, conv_b, qkv_w, qkv_b, out, qbuf, kbuf, vbuf);
    rel_kernel<<<dim3(8192), 256, 0, stream>>>(qbuf, kr_x, kr_y, rxb, ryb);
    attn_kernel<<<dim3(32, 32), 256, 0, stream>>>(qbuf, kbuf, vbuf, rxb, ryb, attc);
    conv1x1_kernel<<<dim3(32, 4), 256, 0, stream>>>(attc, att_w, att_b, out);
}

// Round 2
// 488.046 us; speedup vs baseline: 2.1926x; 2.1926x over previous
//
#include <hip/hip_runtime.h>
#include <hip/hip_bf16.h>
#include <math.h>

#define BN 4
#define CIN 128
#define HH 32
#define WW 32
#define HWP 1024
#define NHEAD 8

typedef __attribute__((ext_vector_type(8))) short s8v;
typedef __attribute__((ext_vector_type(4))) float f32x4;

// ---------------- K1: 3x3 convs (conv_out 256ch + qkv 768ch) ----------------
// grid (32 co-tiles, 32 y, 4 b), block 256 = 32 co x 8 x-slots (4 x each)
__global__ __launch_bounds__(256) void conv3x3_kernel(
    const float* __restrict__ x,
    const float* __restrict__ conv_w, const float* __restrict__ conv_b,
    const float* __restrict__ qkv_w, const float* __restrict__ qkv_b,
    float* __restrict__ out,
    float* __restrict__ qbuf,
    __hip_bfloat16* __restrict__ qbf, __hip_bfloat16* __restrict__ kbf,
    __hip_bfloat16* __restrict__ vtb)
{
    __shared__ float xs[CIN][3][34];   // 52224 B
    const int tid = threadIdx.x;
    const int cotile = blockIdx.x;
    const int y = blockIdx.y;
    const int b = blockIdx.z;

    for (int idx = tid; idx < CIN * 3 * 34; idx += 256) {
        int ci = idx / 102;
        int rem = idx - ci * 102;
        int ky = rem / 34;
        int xc = rem - ky * 34;
        int gy = y + ky - 1;
        int gx = xc - 1;
        float v = 0.f;
        if ((unsigned)gy < 32u && (unsigned)gx < 32u)
            v = x[((b * CIN + ci) * HH + gy) * WW + gx];
        xs[ci][ky][xc] = v;
    }
    __syncthreads();

    const int co_local = tid >> 3;
    const int x0 = (tid & 7) * 4;
    const int co = cotile * 32 + co_local;

    const float* wbase;
    float bias;
    if (co < 256) { wbase = conv_w + co * 1152; bias = conv_b[co]; }
    else         { int c2 = co - 256; wbase = qkv_w + c2 * 1152; bias = qkv_b[c2]; }

    float acc0 = 0.f, acc1 = 0.f, acc2 = 0.f, acc3 = 0.f;
    for (int ci = 0; ci < CIN; ++ci) {
        const float* wp = wbase + ci * 9;
        float w00 = wp[0], w01 = wp[1], w02 = wp[2];
        float w10 = wp[3], w11 = wp[4], w12 = wp[5];
        float w20 = wp[6], w21 = wp[7], w22 = wp[8];

        const float* r0 = &xs[ci][0][x0];
        float a0 = r0[0], a1 = r0[1], a2 = r0[2], a3 = r0[3], a4 = r0[4], a5 = r0[5];
        acc0 += w00 * a0 + w01 * a1 + w02 * a2;
        acc1 += w00 * a1 + w01 * a2 + w02 * a3;
        acc2 += w00 * a2 + w01 * a3 + w02 * a4;
        acc3 += w00 * a3 + w01 * a4 + w02 * a5;

        const float* r1 = &xs[ci][1][x0];
        a0 = r1[0]; a1 = r1[1]; a2 = r1[2]; a3 = r1[3]; a4 = r1[4]; a5 = r1[5];
        acc0 += w10 * a0 + w11 * a1 + w12 * a2;
        acc1 += w10 * a1 + w11 * a2 + w12 * a3;
        acc2 += w10 * a2 + w11 * a3 + w12 * a4;
        acc3 += w10 * a3 + w11 * a4 + w12 * a5;

        const float* r2 = &xs[ci][2][x0];
        a0 = r2[0]; a1 = r2[1]; a2 = r2[2]; a3 = r2[3]; a4 = r2[4]; a5 = r2[5];
        acc0 += w20 * a0 + w21 * a1 + w22 * a2;
        acc1 += w20 * a1 + w21 * a2 + w22 * a3;
        acc2 += w20 * a2 + w21 * a3 + w22 * a4;
        acc3 += w20 * a3 + w21 * a4 + w22 * a5;
    }

    float vals[4] = { acc0 + bias, acc1 + bias, acc2 + bias, acc3 + bias };

    if (co < 256) {
        float* op = out + ((size_t)(b * 512 + co) * HWP) + y * WW + x0;
        op[0] = vals[0]; op[1] = vals[1]; op[2] = vals[2]; op[3] = vals[3];
    } else {
        int c2 = co - 256;
        int which = c2 >> 8;       // 0=q,1=k,2=v
        int cc = c2 & 255;
        int h = cc >> 5, d = cc & 31;
        int bh = b * NHEAD + h;
        if (which == 0) {
            const float scale = 0.17677669529663687f;
            size_t base = ((size_t)bh * HWP + y * WW + x0) * 32 + d;
            float* qp = qbuf + base;
            __hip_bfloat16* qbp = qbf + base;
#pragma unroll
            for (int u = 0; u < 4; ++u) {
                float sv = vals[u] * scale;
                qp[u * 32] = sv;
                qbp[u * 32] = __float2bfloat16(sv);
            }
        } else if (which == 1) {
            size_t base = ((size_t)bh * HWP + y * WW + x0) * 32 + d;
            __hip_bfloat16* kp = kbf + base;
#pragma unroll
            for (int u = 0; u < 4; ++u) kp[u * 32] = __float2bfloat16(vals[u]);
        } else {
            // transposed: vtb[(bh*32 + d)*1024 + pix]
            __hip_bfloat16* vp = vtb + ((size_t)bh * 32 + d) * HWP + y * WW + x0;
#pragma unroll
            for (int u = 0; u < 4; ++u) vp[u] = __float2bfloat16(vals[u]);
        }
    }
}

// ---------------- K2: relative logit row-vectors Rx, Ry ----------------
__global__ __launch_bounds__(256) void rel_kernel(
    const float* __restrict__ qbuf,
    const float* __restrict__ kr_x, const float* __restrict__ kr_y,
    float* __restrict__ rx, float* __restrict__ ry)
{
    int g = blockIdx.x * 256 + threadIdx.x;   // 32 bh * 1024 i * 64 m
    int m = g & 63;
    int i = (g >> 6) & 1023;
    int bh = g >> 16;
    int yi = i >> 5, xi = i & 31;

    const float* qrow;
    const float* kr;
    float* dst;
    if (m < 32) {
        qrow = qbuf + ((size_t)bh * HWP + i) * 32;
        kr = kr_x + (m - xi + 31) * 32;
        dst = rx + ((size_t)bh * HWP + i) * 32 + m;
    } else {
        int y2 = m - 32;
        qrow = qbuf + ((size_t)bh * HWP + (xi * 32 + yi)) * 32;
        kr = kr_y + (y2 - xi + 31) * 32;
        dst = ry + ((size_t)bh * HWP + i) * 32 + y2;
    }
    float s = 0.f;
#pragma unroll
    for (int d = 0; d < 32; d += 4) {
        float4 a = *(const float4*)(qrow + d);
        float4 c = *(const float4*)(kr + d);
        s += a.x * c.x + a.y * c.y + a.z * c.z + a.w * c.w;
    }
    *dst = s;
}

// ---------------- K3: MFMA flash attention ----------------
// grid (16 i-blocks, 32 bh), block 256 = 4 waves; wave w handles i-tile of 16
// rows (i0 = (blk*4+w)*16). j loop in tiles of 32 (yj = jt constant per tile).
__global__ __launch_bounds__(256) void attn_kernel(
    const __hip_bfloat16* __restrict__ qbf, const __hip_bfloat16* __restrict__ kbf,
    const __hip_bfloat16* __restrict__ vtb,
    const float* __restrict__ rx, const float* __restrict__ ry,
    float* __restrict__ attc)
{
    // per-wave P buffer: 16 rows x 48 bf16 (stride 96B: 16B-aligned rows,
    // quad bank offsets {0,24,16,8} disjoint -> conflict-free b16 writes)
    __shared__ __align__(16) __hip_bfloat16 Pb[4][16][48];

    const int tid = threadIdx.x;
    const int wv = tid >> 6;
    const int lane = tid & 63;
    const int n16 = lane & 15;        // col within tile
    const int quad = lane >> 4;       // 0..3
    const int bh = blockIdx.y;
    const int i0 = (blockIdx.x * 4 + wv) * 16;

    // ---- Q fragment (A layout): row i0+n16, k = quad*8..+8
    const size_t qoff = ((size_t)bh * HWP + i0 + n16) * 32 + quad * 8;
    s8v aq = *reinterpret_cast<const s8v*>(qbf + qoff);

    // ---- Rx preload: rows i0+quad*4+r, col n16 / n16+16 (constant over jt)
    float rx0[4], rx1[4];
#pragma unroll
    for (int r = 0; r < 4; ++r) {
        const float* rp = rx + ((size_t)bh * HWP + i0 + quad * 4 + r) * 32;
        rx0[r] = rp[n16];
        rx1[r] = rp[n16 + 16];
    }
    const float* ryrow[4];
#pragma unroll
    for (int r = 0; r < 4; ++r)
        ryrow[r] = ry + ((size_t)bh * HWP + i0 + quad * 4 + r) * 32;

    float mrun[4], lrun[4];
    f32x4 O0 = {0.f, 0.f, 0.f, 0.f}, O1 = {0.f, 0.f, 0.f, 0.f};
#pragma unroll
    for (int r = 0; r < 4; ++r) { mrun[r] = -INFINITY; lrun[r] = 0.f; }

    const __hip_bfloat16* kbase = kbf + (size_t)bh * HWP * 32;
    const __hip_bfloat16* vbase = vtb + (size_t)bh * 32 * HWP;

    for (int jt = 0; jt < 32; ++jt) {
        const int j0 = jt * 32;
        // K fragments (B layout): rows j0+n16 and j0+16+n16
        s8v bk0 = *reinterpret_cast<const s8v*>(kbase + ((size_t)(j0 + n16) * 32 + quad * 8));
        s8v bk1 = *reinterpret_cast<const s8v*>(kbase + ((size_t)(j0 + 16 + n16) * 32 + quad * 8));
        // Vt fragments for PV (B layout): B[k=j][n=d] = Vt[d][j0+k]
        s8v bv0 = *reinterpret_cast<const s8v*>(vbase + ((size_t)n16 * HWP + j0 + quad * 8));
        s8v bv1 = *reinterpret_cast<const s8v*>(vbase + ((size_t)(n16 + 16) * HWP + j0 + quad * 8));

        f32x4 s0 = {0.f, 0.f, 0.f, 0.f}, s1 = {0.f, 0.f, 0.f, 0.f};
        s0 = __builtin_amdgcn_mfma_f32_16x16x32_bf16(aq, bk0, s0, 0, 0, 0);
        s1 = __builtin_amdgcn_mfma_f32_16x16x32_bf16(aq, bk1, s1, 0, 0, 0);

        float p0[4], p1[4], alpha[4];
#pragma unroll
        for (int r = 0; r < 4; ++r) {
            float ryv = ryrow[r][jt];
            float a = s0[r] + rx0[r] + ryv;
            float b = s1[r] + rx1[r] + ryv;
            p0[r] = a; p1[r] = b;
            float t = fmaxf(a, b);
            t = fmaxf(t, __shfl_xor(t, 1));
            t = fmaxf(t, __shfl_xor(t, 2));
            t = fmaxf(t, __shfl_xor(t, 4));
            t = fmaxf(t, __shfl_xor(t, 8));
            float mnew = fmaxf(mrun[r], t);
            alpha[r] = __expf(mrun[r] - mnew);
            mrun[r] = mnew;
        }
#pragma unroll
        for (int r = 0; r < 4; ++r) {
            float a = __expf(p0[r] - mrun[r]);
            float b = __expf(p1[r] - mrun[r]);
            p0[r] = a; p1[r] = b;
            float ts = a + b;
            ts += __shfl_xor(ts, 1);
            ts += __shfl_xor(ts, 2);
            ts += __shfl_xor(ts, 4);
            ts += __shfl_xor(ts, 8);
            lrun[r] = lrun[r] * alpha[r] + ts;
            O0[r] *= alpha[r];
            O1[r] *= alpha[r];
        }
        // C-layout -> A-layout via wave-private LDS
#pragma unroll
        for (int r = 0; r < 4; ++r) {
            Pb[wv][quad * 4 + r][n16]      = __float2bfloat16(p0[r]);
            Pb[wv][quad * 4 + r][n16 + 16] = __float2bfloat16(p1[r]);
        }
        s8v pA = *reinterpret_cast<const s8v*>(&Pb[wv][n16][quad * 8]);
        O0 = __builtin_amdgcn_mfma_f32_16x16x32_bf16(pA, bv0, O0, 0, 0, 0);
        O1 = __builtin_amdgcn_mfma_f32_16x16x32_bf16(pA, bv1, O1, 0, 0, 0);
    }

    const int b = bh >> 3, h = bh & 7;
#pragma unroll
    for (int r = 0; r < 4; ++r) {
        int i = i0 + quad * 4 + r;
        int yi = i >> 5, xi = i & 31;
        float inv = 1.0f / lrun[r];
        float* op = attc + ((size_t)(b * 256 + h * 32 + yi) * 32 + xi) * 32;
        op[n16] = O0[r] * inv;
        op[n16 + 16] = O1[r] * inv;
    }
}

// ---------------- K4: 1x1 conv (256 -> 256) on scrambled att ----------------
__global__ __launch_bounds__(256) void conv1x1_kernel(
    const float* __restrict__ attc,
    const float* __restrict__ att_w, const float* __restrict__ att_b,
    float* __restrict__ out)
{
    __shared__ float ins[256][33];  // 33792 B
    const int tid = threadIdx.x;
    const int y = blockIdx.x;
    const int b = blockIdx.y;

    for (int idx = tid; idx < 256 * 32; idx += 256) {
        int c = idx >> 5, xx = idx & 31;
        ins[c][xx] = attc[((size_t)(b * 256 + c) * 32 + y) * 32 + xx];
    }
    __syncthreads();

    const int xx = tid & 31;
    const int og = tid >> 5;
    float acc[32];
#pragma unroll
    for (int oo = 0; oo < 32; ++oo) acc[oo] = att_b[og * 32 + oo];

    for (int c = 0; c < 256; ++c) {
        float iv = ins[c][xx];
        const float* wp = att_w + (size_t)(og * 32) * 256 + c;
#pragma unroll
        for (int oo = 0; oo < 32; ++oo)
            acc[oo] += wp[(size_t)oo * 256] * iv;
    }

#pragma unroll
    for (int oo = 0; oo < 32; ++oo) {
        int o = og * 32 + oo;
        out[((size_t)(b * 512 + 256 + o) * HWP) + y * 32 + xx] = acc[oo];
    }
}

extern "C" void kernel_launch(void* const* d_in, const int* in_sizes, int n_in,
                              void* d_out, int out_size, void* d_ws, size_t ws_size,
                              hipStream_t stream) {
    const float* x      = (const float*)d_in[0];
    const float* conv_w = (const float*)d_in[1];
    const float* conv_b = (const float*)d_in[2];
    const float* qkv_w  = (const float*)d_in[3];
    const float* qkv_b  = (const float*)d_in[4];
    const float* att_w  = (const float*)d_in[5];
    const float* att_b  = (const float*)d_in[6];
    const float* kr_x   = (const float*)d_in[7];
    const float* kr_y   = (const float*)d_in[8];
    float* out = (float*)d_out;

    float* ws = (float*)d_ws;
    const size_t M = 1u << 20;   // 1M floats = 4 MB
    float* qbuf = ws + 0 * M;                 // fp32 q (for rel)
    float* rxb  = ws + 1 * M;
    float* ryb  = ws + 2 * M;
    float* attc = ws + 3 * M;
    __hip_bfloat16* qbf = (__hip_bfloat16*)(ws + 4 * M);                 // 2 MB
    __hip_bfloat16* kbf = (__hip_bfloat16*)(ws + 4 * M + M / 2);         // 2 MB
    __hip_bfloat16* vtb = (__hip_bfloat16*)(ws + 5 * M);                 // 2 MB (transposed)

    conv3x3_kernel<<<dim3(32, 32, 4), 256, 0, stream>>>(
        x, conv_w, conv_b, qkv_w, qkv_b, out, qbuf, qbf, kbf, vtb);
    rel_kernel<<<dim3(8192), 256, 0, stream>>>(qbuf, kr_x, kr_y, rxb, ryb);
    attn_kernel<<<dim3(16, 32), 256, 0, stream>>>(qbf, kbf, vtb, rxb, ryb, attc);
    conv1x1_kernel<<<dim3(32, 4), 256, 0, stream>>>(attc, att_w, att_b, out);
}

// Round 3
// 312.889 us; speedup vs baseline: 3.4201x; 1.5598x over previous
//
#include <hip/hip_runtime.h>
#include <hip/hip_bf16.h>
#include <math.h>

#define BN 4
#define CIN 128
#define HH 32
#define WW 32
#define HWP 1024
#define NHEAD 8

typedef __attribute__((ext_vector_type(8))) short s8v;
typedef __attribute__((ext_vector_type(4))) float f32x4;

__device__ __forceinline__ float bf2f(short h) {
    union { unsigned u; float f; } v;
    v.u = ((unsigned)(unsigned short)h) << 16;
    return v.f;
}

// ---------------- P1: x (NCHW fp32) -> xT[b][34][34][128] bf16, zero halo ----
// grid (34, 4), block 256
__global__ __launch_bounds__(256) void prep_xT(
    const float* __restrict__ x, __hip_bfloat16* __restrict__ xT)
{
    __shared__ float xs[CIN][33];
    const int yy = blockIdx.x;
    const int b = blockIdx.y;
    const int tid = threadIdx.x;
    const bool inner = (yy >= 1 && yy <= 32);

    if (inner) {
        for (int idx = tid; idx < CIN * 32; idx += 256) {
            int ci = idx >> 5, xx = idx & 31;
            xs[ci][xx] = x[((size_t)(b * CIN + ci) * HH + (yy - 1)) * WW + xx];
        }
    }
    __syncthreads();

    for (int idx = tid; idx < 34 * 128; idx += 256) {
        int xx = idx >> 7, ci = idx & 127;
        float v = 0.f;
        if (inner && xx >= 1 && xx <= 32) v = xs[ci][xx - 1];
        xT[((size_t)(b * 34 + yy) * 34 + xx) * 128 + ci] = __float2bfloat16(v);
    }
}

// ---------------- P2: weights -> Wb[1024][1152] bf16, K order (ky,kx,ci) ----
__global__ __launch_bounds__(256) void prep_w(
    const float* __restrict__ conv_w, const float* __restrict__ qkv_w,
    __hip_bfloat16* __restrict__ Wb)
{
    int g = blockIdx.x * 256 + threadIdx.x;    // 1024*1152
    int co = g / 1152;
    int k = g - co * 1152;
    int kk = k >> 7, ci = k & 127;             // kk = ky*3+kx
    float v;
    if (co < 256) v = conv_w[((size_t)(co * 128 + ci) * 9) + kk];
    else          v = qkv_w[((size_t)((co - 256) * 128 + ci) * 9) + kk];
    Wb[(size_t)co * 1152 + k] = __float2bfloat16(v);
}

// ---------------- K1: MFMA implicit-GEMM 3x3 conv ----------------
// C[co][pix] = Wb[co][.] . im2col; grid (8 co-tiles, 8 y-tiles, 4 b), 4 waves
__global__ __launch_bounds__(256) void conv_gemm(
    const __hip_bfloat16* __restrict__ Wb, const __hip_bfloat16* __restrict__ xT,
    const float* __restrict__ conv_b, const float* __restrict__ qkv_b,
    float* __restrict__ out,
    __hip_bfloat16* __restrict__ qbf, __hip_bfloat16* __restrict__ kbf,
    __hip_bfloat16* __restrict__ vtb)
{
    __shared__ __align__(16) __hip_bfloat16 As[128 * 40];  // stride 40 (80B, 16B-aligned)
    __shared__ __align__(16) __hip_bfloat16 Bs[128 * 40];

    const int tid = threadIdx.x;
    const int wv = tid >> 6;
    const int lane = tid & 63;
    const int n16 = lane & 15;
    const int quad = lane >> 4;
    const int co0 = blockIdx.x * 128;
    const int y0 = blockIdx.y * 4;
    const int b = blockIdx.z;

    f32x4 acc[4][4];
#pragma unroll
    for (int i = 0; i < 4; ++i)
#pragma unroll
        for (int j = 0; j < 4; ++j) acc[i][j] = (f32x4){0.f, 0.f, 0.f, 0.f};

    const int mh = wv >> 1, nh = wv & 1;

    for (int s = 0; s < 36; ++s) {
        const int kk = s >> 2;            // ky*3+kx
        const int ky = kk / 3, kx = kk - ky * 3;
        const int ci0 = (s & 3) * 32;
        const int k0 = kk * 128 + ci0;

        __syncthreads();
        // stage A: 128 co x 32 k  (512 chunks of 8 bf16)
#pragma unroll
        for (int c = tid; c < 512; c += 256) {
            int co = c >> 2, h = c & 3;
            s8v v = *reinterpret_cast<const s8v*>(
                Wb + (size_t)(co0 + co) * 1152 + k0 + h * 8);
            *reinterpret_cast<s8v*>(&As[co * 40 + h * 8]) = v;
        }
        // stage B: 128 pix x 32 ci
#pragma unroll
        for (int c = tid; c < 512; c += 256) {
            int p = c >> 2, h = c & 3;
            s8v v = *reinterpret_cast<const s8v*>(
                xT + ((size_t)(b * 34 + y0 + (p >> 5) + ky) * 34 + (p & 31) + kx) * 128
                   + ci0 + h * 8);
            *reinterpret_cast<s8v*>(&Bs[p * 40 + h * 8]) = v;
        }
        __syncthreads();

        s8v af[4], bfr[4];
#pragma unroll
        for (int mt = 0; mt < 4; ++mt)
            af[mt] = *reinterpret_cast<const s8v*>(&As[(mh * 64 + mt * 16 + n16) * 40 + quad * 8]);
#pragma unroll
        for (int nt = 0; nt < 4; ++nt)
            bfr[nt] = *reinterpret_cast<const s8v*>(&Bs[(nh * 64 + nt * 16 + n16) * 40 + quad * 8]);
#pragma unroll
        for (int mt = 0; mt < 4; ++mt)
#pragma unroll
            for (int nt = 0; nt < 4; ++nt)
                acc[mt][nt] = __builtin_amdgcn_mfma_f32_16x16x32_bf16(af[mt], bfr[nt], acc[mt][nt], 0, 0, 0);
    }

    // epilogue: co = coBase + mt*16 + quad*4 + r ; pix = pixBase + nt*16 + n16
    const int coBase = co0 + mh * 64;
    const int pixBase = y0 * 32 + nh * 64;
    const int seg = coBase >> 8;     // 0=conv_out, 1=q, 2=k, 3=v (wave-uniform)

    if (seg == 0) {
#pragma unroll
        for (int mt = 0; mt < 4; ++mt)
#pragma unroll
            for (int r = 0; r < 4; ++r) {
                int co = coBase + mt * 16 + quad * 4 + r;
                float bias = conv_b[co];
                float* op = out + (size_t)(b * 512 + co) * HWP + pixBase;
#pragma unroll
                for (int nt = 0; nt < 4; ++nt)
                    op[nt * 16 + n16] = acc[mt][nt][r] + bias;
            }
    } else if (seg == 1) {
        const float scale = 0.17677669529663687f;
#pragma unroll
        for (int mt = 0; mt < 4; ++mt)
#pragma unroll
            for (int r = 0; r < 4; ++r) {
                int c2 = coBase - 256 + mt * 16 + quad * 4 + r;
                float bias = qkv_b[c2];
                int h = c2 >> 5, d = c2 & 31;
                int bh = b * NHEAD + h;
#pragma unroll
                for (int nt = 0; nt < 4; ++nt) {
                    int pix = pixBase + nt * 16 + n16;
                    qbf[((size_t)bh * HWP + pix) * 32 + d] =
                        __float2bfloat16((acc[mt][nt][r] + bias) * scale);
                }
            }
    } else if (seg == 2) {
#pragma unroll
        for (int mt = 0; mt < 4; ++mt)
#pragma unroll
            for (int r = 0; r < 4; ++r) {
                int c2 = coBase - 512 + mt * 16 + quad * 4 + r;
                float bias = qkv_b[c2 + 256];
                int h = c2 >> 5, d = c2 & 31;
                int bh = b * NHEAD + h;
#pragma unroll
                for (int nt = 0; nt < 4; ++nt) {
                    int pix = pixBase + nt * 16 + n16;
                    kbf[((size_t)bh * HWP + pix) * 32 + d] =
                        __float2bfloat16(acc[mt][nt][r] + bias);
                }
            }
    } else {
#pragma unroll
        for (int mt = 0; mt < 4; ++mt)
#pragma unroll
            for (int r = 0; r < 4; ++r) {
                int c2 = coBase - 768 + mt * 16 + quad * 4 + r;
                float bias = qkv_b[c2 + 512];
                int h = c2 >> 5, d = c2 & 31;
                int bh = b * NHEAD + h;
                __hip_bfloat16* vp = vtb + ((size_t)bh * 32 + d) * HWP + pixBase;
#pragma unroll
                for (int nt = 0; nt < 4; ++nt)
                    vp[nt * 16 + n16] = __float2bfloat16(acc[mt][nt][r] + bias);
            }
    }
}

// ---------------- K2: relative logit row-vectors Rx, Ry (bf16 q) ----------------
__global__ __launch_bounds__(256) void rel_kernel(
    const __hip_bfloat16* __restrict__ qbf,
    const float* __restrict__ kr_x, const float* __restrict__ kr_y,
    float* __restrict__ rx, float* __restrict__ ry)
{
    int g = blockIdx.x * 256 + threadIdx.x;   // 32 bh * 1024 i * 64 m
    int m = g & 63;
    int i = (g >> 6) & 1023;
    int bh = g >> 16;
    int yi = i >> 5, xi = i & 31;

    const __hip_bfloat16* qrow;
    const float* kr;
    float* dst;
    if (m < 32) {
        qrow = qbf + ((size_t)bh * HWP + i) * 32;
        kr = kr_x + (m - xi + 31) * 32;
        dst = rx + ((size_t)bh * HWP + i) * 32 + m;
    } else {
        int y2 = m - 32;
        qrow = qbf + ((size_t)bh * HWP + (xi * 32 + yi)) * 32;
        kr = kr_y + (y2 - xi + 31) * 32;
        dst = ry + ((size_t)bh * HWP + i) * 32 + y2;
    }
    float s = 0.f;
#pragma unroll
    for (int c = 0; c < 4; ++c) {
        s8v qa = *reinterpret_cast<const s8v*>(qrow + c * 8);
        const float* kp = kr + c * 8;
#pragma unroll
        for (int j = 0; j < 8; ++j) s += bf2f(qa[j]) * kp[j];
    }
    *dst = s;
}

// ---------------- K3: MFMA flash attention ----------------
__global__ __launch_bounds__(256) void attn_kernel(
    const __hip_bfloat16* __restrict__ qbf, const __hip_bfloat16* __restrict__ kbf,
    const __hip_bfloat16* __restrict__ vtb,
    const float* __restrict__ rx, const float* __restrict__ ry,
    float* __restrict__ attc)
{
    __shared__ __align__(16) __hip_bfloat16 Pb[4][16][48];

    const int tid = threadIdx.x;
    const int wv = tid >> 6;
    const int lane = tid & 63;
    const int n16 = lane & 15;
    const int quad = lane >> 4;
    const int bh = blockIdx.y;
    const int i0 = (blockIdx.x * 4 + wv) * 16;

    const size_t qoff = ((size_t)bh * HWP + i0 + n16) * 32 + quad * 8;
    s8v aq = *reinterpret_cast<const s8v*>(qbf + qoff);

    float rx0[4], rx1[4];
#pragma unroll
    for (int r = 0; r < 4; ++r) {
        const float* rp = rx + ((size_t)bh * HWP + i0 + quad * 4 + r) * 32;
        rx0[r] = rp[n16];
        rx1[r] = rp[n16 + 16];
    }
    const float* ryrow[4];
#pragma unroll
    for (int r = 0; r < 4; ++r)
        ryrow[r] = ry + ((size_t)bh * HWP + i0 + quad * 4 + r) * 32;

    float mrun[4], lrun[4];
    f32x4 O0 = {0.f, 0.f, 0.f, 0.f}, O1 = {0.f, 0.f, 0.f, 0.f};
#pragma unroll
    for (int r = 0; r < 4; ++r) { mrun[r] = -INFINITY; lrun[r] = 0.f; }

    const __hip_bfloat16* kbase = kbf + (size_t)bh * HWP * 32;
    const __hip_bfloat16* vbase = vtb + (size_t)bh * 32 * HWP;

    for (int jt = 0; jt < 32; ++jt) {
        const int j0 = jt * 32;
        s8v bk0 = *reinterpret_cast<const s8v*>(kbase + ((size_t)(j0 + n16) * 32 + quad * 8));
        s8v bk1 = *reinterpret_cast<const s8v*>(kbase + ((size_t)(j0 + 16 + n16) * 32 + quad * 8));
        s8v bv0 = *reinterpret_cast<const s8v*>(vbase + ((size_t)n16 * HWP + j0 + quad * 8));
        s8v bv1 = *reinterpret_cast<const s8v*>(vbase + ((size_t)(n16 + 16) * HWP + j0 + quad * 8));

        f32x4 s0 = {0.f, 0.f, 0.f, 0.f}, s1 = {0.f, 0.f, 0.f, 0.f};
        s0 = __builtin_amdgcn_mfma_f32_16x16x32_bf16(aq, bk0, s0, 0, 0, 0);
        s1 = __builtin_amdgcn_mfma_f32_16x16x32_bf16(aq, bk1, s1, 0, 0, 0);

        float p0[4], p1[4], alpha[4];
#pragma unroll
        for (int r = 0; r < 4; ++r) {
            float ryv = ryrow[r][jt];
            float a = s0[r] + rx0[r] + ryv;
            float b = s1[r] + rx1[r] + ryv;
            p0[r] = a; p1[r] = b;
            float t = fmaxf(a, b);
            t = fmaxf(t, __shfl_xor(t, 1));
            t = fmaxf(t, __shfl_xor(t, 2));
            t = fmaxf(t, __shfl_xor(t, 4));
            t = fmaxf(t, __shfl_xor(t, 8));
            float mnew = fmaxf(mrun[r], t);
            alpha[r] = __expf(mrun[r] - mnew);
            mrun[r] = mnew;
        }
#pragma unroll
        for (int r = 0; r < 4; ++r) {
            float a = __expf(p0[r] - mrun[r]);
            float b = __expf(p1[r] - mrun[r]);
            p0[r] = a; p1[r] = b;
            float ts = a + b;
            ts += __shfl_xor(ts, 1);
            ts += __shfl_xor(ts, 2);
            ts += __shfl_xor(ts, 4);
            ts += __shfl_xor(ts, 8);
            lrun[r] = lrun[r] * alpha[r] + ts;
            O0[r] *= alpha[r];
            O1[r] *= alpha[r];
        }
#pragma unroll
        for (int r = 0; r < 4; ++r) {
            Pb[wv][quad * 4 + r][n16]      = __float2bfloat16(p0[r]);
            Pb[wv][quad * 4 + r][n16 + 16] = __float2bfloat16(p1[r]);
        }
        s8v pA = *reinterpret_cast<const s8v*>(&Pb[wv][n16][quad * 8]);
        O0 = __builtin_amdgcn_mfma_f32_16x16x32_bf16(pA, bv0, O0, 0, 0, 0);
        O1 = __builtin_amdgcn_mfma_f32_16x16x32_bf16(pA, bv1, O1, 0, 0, 0);
    }

    const int b = bh >> 3, h = bh & 7;
#pragma unroll
    for (int r = 0; r < 4; ++r) {
        int i = i0 + quad * 4 + r;
        int yi = i >> 5, xi = i & 31;
        float inv = 1.0f / lrun[r];
        float* op = attc + ((size_t)(b * 256 + h * 32 + yi) * 32 + xi) * 32;
        op[n16] = O0[r] * inv;
        op[n16 + 16] = O1[r] * inv;
    }
}

// ---------------- K4: 1x1 conv (256 -> 256) on scrambled att ----------------
__global__ __launch_bounds__(256) void conv1x1_kernel(
    const float* __restrict__ attc,
    const float* __restrict__ att_w, const float* __restrict__ att_b,
    float* __restrict__ out)
{
    __shared__ float ins[256][33];
    const int tid = threadIdx.x;
    const int y = blockIdx.x;
    const int b = blockIdx.y;

    for (int idx = tid; idx < 256 * 32; idx += 256) {
        int c = idx >> 5, xx = idx & 31;
        ins[c][xx] = attc[((size_t)(b * 256 + c) * 32 + y) * 32 + xx];
    }
    __syncthreads();

    const int xx = tid & 31;
    const int og = tid >> 5;
    float acc[32];
#pragma unroll
    for (int oo = 0; oo < 32; ++oo) acc[oo] = att_b[og * 32 + oo];

    for (int c = 0; c < 256; ++c) {
        float iv = ins[c][xx];
        const float* wp = att_w + (size_t)(og * 32) * 256 + c;
#pragma unroll
        for (int oo = 0; oo < 32; ++oo)
            acc[oo] += wp[(size_t)oo * 256] * iv;
    }

#pragma unroll
    for (int oo = 0; oo < 32; ++oo) {
        int o = og * 32 + oo;
        out[((size_t)(b * 512 + 256 + o) * HWP) + y * 32 + xx] = acc[oo];
    }
}

extern "C" void kernel_launch(void* const* d_in, const int* in_sizes, int n_in,
                              void* d_out, int out_size, void* d_ws, size_t ws_size,
                              hipStream_t stream) {
    const float* x      = (const float*)d_in[0];
    const float* conv_w = (const float*)d_in[1];
    const float* conv_b = (const float*)d_in[2];
    const float* qkv_w  = (const float*)d_in[3];
    const float* qkv_b  = (const float*)d_in[4];
    const float* att_w  = (const float*)d_in[5];
    const float* att_b  = (const float*)d_in[6];
    const float* kr_x   = (const float*)d_in[7];
    const float* kr_y   = (const float*)d_in[8];
    float* out = (float*)d_out;

    float* ws = (float*)d_ws;
    const size_t M = 1u << 20;   // 1M floats = 4 MB
    float* rxb  = ws + 0 * M;
    float* ryb  = ws + 1 * M;
    float* attc = ws + 2 * M;
    __hip_bfloat16* qbf = (__hip_bfloat16*)(ws + 3 * M);           // 2 MB
    __hip_bfloat16* kbf = (__hip_bfloat16*)(ws + 3 * M + M / 2);   // 2 MB
    __hip_bfloat16* vtb = (__hip_bfloat16*)(ws + 4 * M);           // 2 MB
    __hip_bfloat16* xT  = (__hip_bfloat16*)(ws + 4 * M + M / 2);   // 4*34*34*128*2 = 1.13 MB
    __hip_bfloat16* Wb  = (__hip_bfloat16*)(ws + 5 * M);           // 1024*1152*2 = 2.25 MB

    prep_xT<<<dim3(34, 4), 256, 0, stream>>>(x, xT);
    prep_w<<<dim3(4608), 256, 0, stream>>>(conv_w, qkv_w, Wb);
    conv_gemm<<<dim3(8, 8, 4), 256, 0, stream>>>(
        Wb, xT, conv_b, qkv_b, out, qbf, kbf, vtb);
    rel_kernel<<<dim3(8192), 256, 0, stream>>>(qbf, kr_x, kr_y, rxb, ryb);
    attn_kernel<<<dim3(16, 32), 256, 0, stream>>>(qbf, kbf, vtb, rxb, ryb, attc);
    conv1x1_kernel<<<dim3(32, 4), 256, 0, stream>>>(attc, att_w, att_b, out);
}

// Round 4
// 218.235 us; speedup vs baseline: 4.9035x; 1.4337x over previous
//
#include <hip/hip_runtime.h>
#include <hip/hip_bf16.h>
#include <math.h>

#define BN 4
#define CIN 128
#define HH 32
#define WW 32
#define HWP 1024
#define NHEAD 8

typedef __attribute__((ext_vector_type(8))) short s8v;
typedef __attribute__((ext_vector_type(4))) float f32x4;

__device__ __forceinline__ float bf2f(short h) {
    union { unsigned u; float f; } v;
    v.u = ((unsigned)(unsigned short)h) << 16;
    return v.f;
}

// ---------------- P1: x (NCHW fp32) -> xT[b][34][34][128] bf16, zero halo ----
__global__ __launch_bounds__(256) void prep_xT(
    const float* __restrict__ x, __hip_bfloat16* __restrict__ xT)
{
    __shared__ float xs[CIN][33];
    const int yy = blockIdx.x;
    const int b = blockIdx.y;
    const int tid = threadIdx.x;
    const bool inner = (yy >= 1 && yy <= 32);

    if (inner) {
        for (int idx = tid; idx < CIN * 32; idx += 256) {
            int ci = idx >> 5, xx = idx & 31;
            xs[ci][xx] = x[((size_t)(b * CIN + ci) * HH + (yy - 1)) * WW + xx];
        }
    }
    __syncthreads();

    for (int idx = tid; idx < 34 * 128; idx += 256) {
        int xx = idx >> 7, ci = idx & 127;
        float v = 0.f;
        if (inner && xx >= 1 && xx <= 32) v = xs[ci][xx - 1];
        xT[((size_t)(b * 34 + yy) * 34 + xx) * 128 + ci] = __float2bfloat16(v);
    }
}

// ---------------- P2: weights -> Wb[1024][1152] bf16, K order (ky,kx,ci) ----
__global__ __launch_bounds__(256) void prep_w(
    const float* __restrict__ conv_w, const float* __restrict__ qkv_w,
    __hip_bfloat16* __restrict__ Wb)
{
    int g = blockIdx.x * 256 + threadIdx.x;    // 1024*1152
    int co = g / 1152;
    int k = g - co * 1152;
    int kk = k >> 7, ci = k & 127;             // kk = ky*3+kx
    float v;
    if (co < 256) v = conv_w[((size_t)(co * 128 + ci) * 9) + kk];
    else          v = qkv_w[((size_t)((co - 256) * 128 + ci) * 9) + kk];
    Wb[(size_t)co * 1152 + k] = __float2bfloat16(v);
}

// ---------------- P3: att_w fp32 -> bf16 ----------------
__global__ __launch_bounds__(256) void prep_aw(
    const float* __restrict__ att_w, __hip_bfloat16* __restrict__ Wab)
{
    int g = blockIdx.x * 256 + threadIdx.x;    // 65536
    Wab[g] = __float2bfloat16(att_w[g]);
}

// ---------------- K1: MFMA implicit-GEMM 3x3 conv ----------------
__global__ __launch_bounds__(256) void conv_gemm(
    const __hip_bfloat16* __restrict__ Wb, const __hip_bfloat16* __restrict__ xT,
    const float* __restrict__ conv_b, const float* __restrict__ qkv_b,
    float* __restrict__ out,
    __hip_bfloat16* __restrict__ qbf, __hip_bfloat16* __restrict__ kbf,
    __hip_bfloat16* __restrict__ vtb)
{
    __shared__ __align__(16) __hip_bfloat16 As[128 * 40];
    __shared__ __align__(16) __hip_bfloat16 Bs[128 * 40];

    const int tid = threadIdx.x;
    const int wv = tid >> 6;
    const int lane = tid & 63;
    const int n16 = lane & 15;
    const int quad = lane >> 4;
    const int co0 = blockIdx.x * 128;
    const int y0 = blockIdx.y * 4;
    const int b = blockIdx.z;

    f32x4 acc[4][4];
#pragma unroll
    for (int i = 0; i < 4; ++i)
#pragma unroll
        for (int j = 0; j < 4; ++j) acc[i][j] = (f32x4){0.f, 0.f, 0.f, 0.f};

    const int mh = wv >> 1, nh = wv & 1;

    for (int s = 0; s < 36; ++s) {
        const int kk = s >> 2;
        const int ky = kk / 3, kx = kk - ky * 3;
        const int ci0 = (s & 3) * 32;
        const int k0 = kk * 128 + ci0;

        __syncthreads();
#pragma unroll
        for (int c = tid; c < 512; c += 256) {
            int co = c >> 2, h = c & 3;
            s8v v = *reinterpret_cast<const s8v*>(
                Wb + (size_t)(co0 + co) * 1152 + k0 + h * 8);
            *reinterpret_cast<s8v*>(&As[co * 40 + h * 8]) = v;
        }
#pragma unroll
        for (int c = tid; c < 512; c += 256) {
            int p = c >> 2, h = c & 3;
            s8v v = *reinterpret_cast<const s8v*>(
                xT + ((size_t)(b * 34 + y0 + (p >> 5) + ky) * 34 + (p & 31) + kx) * 128
                   + ci0 + h * 8);
            *reinterpret_cast<s8v*>(&Bs[p * 40 + h * 8]) = v;
        }
        __syncthreads();

        s8v af[4], bfr[4];
#pragma unroll
        for (int mt = 0; mt < 4; ++mt)
            af[mt] = *reinterpret_cast<const s8v*>(&As[(mh * 64 + mt * 16 + n16) * 40 + quad * 8]);
#pragma unroll
        for (int nt = 0; nt < 4; ++nt)
            bfr[nt] = *reinterpret_cast<const s8v*>(&Bs[(nh * 64 + nt * 16 + n16) * 40 + quad * 8]);
#pragma unroll
        for (int mt = 0; mt < 4; ++mt)
#pragma unroll
            for (int nt = 0; nt < 4; ++nt)
                acc[mt][nt] = __builtin_amdgcn_mfma_f32_16x16x32_bf16(af[mt], bfr[nt], acc[mt][nt], 0, 0, 0);
    }

    const int coBase = co0 + mh * 64;
    const int pixBase = y0 * 32 + nh * 64;
    const int seg = coBase >> 8;

    if (seg == 0) {
#pragma unroll
        for (int mt = 0; mt < 4; ++mt)
#pragma unroll
            for (int r = 0; r < 4; ++r) {
                int co = coBase + mt * 16 + quad * 4 + r;
                float bias = conv_b[co];
                float* op = out + (size_t)(b * 512 + co) * HWP + pixBase;
#pragma unroll
                for (int nt = 0; nt < 4; ++nt)
                    op[nt * 16 + n16] = acc[mt][nt][r] + bias;
            }
    } else if (seg == 1) {
        const float scale = 0.17677669529663687f;
#pragma unroll
        for (int mt = 0; mt < 4; ++mt)
#pragma unroll
            for (int r = 0; r < 4; ++r) {
                int c2 = coBase - 256 + mt * 16 + quad * 4 + r;
                float bias = qkv_b[c2];
                int h = c2 >> 5, d = c2 & 31;
                int bh = b * NHEAD + h;
#pragma unroll
                for (int nt = 0; nt < 4; ++nt) {
                    int pix = pixBase + nt * 16 + n16;
                    qbf[((size_t)bh * HWP + pix) * 32 + d] =
                        __float2bfloat16((acc[mt][nt][r] + bias) * scale);
                }
            }
    } else if (seg == 2) {
#pragma unroll
        for (int mt = 0; mt < 4; ++mt)
#pragma unroll
            for (int r = 0; r < 4; ++r) {
                int c2 = coBase - 512 + mt * 16 + quad * 4 + r;
                float bias = qkv_b[c2 + 256];
                int h = c2 >> 5, d = c2 & 31;
                int bh = b * NHEAD + h;
#pragma unroll
                for (int nt = 0; nt < 4; ++nt) {
                    int pix = pixBase + nt * 16 + n16;
                    kbf[((size_t)bh * HWP + pix) * 32 + d] =
                        __float2bfloat16(acc[mt][nt][r] + bias);
                }
            }
    } else {
#pragma unroll
        for (int mt = 0; mt < 4; ++mt)
#pragma unroll
            for (int r = 0; r < 4; ++r) {
                int c2 = coBase - 768 + mt * 16 + quad * 4 + r;
                float bias = qkv_b[c2 + 512];
                int h = c2 >> 5, d = c2 & 31;
                int bh = b * NHEAD + h;
                __hip_bfloat16* vp = vtb + ((size_t)bh * 32 + d) * HWP + pixBase;
#pragma unroll
                for (int nt = 0; nt < 4; ++nt)
                    vp[nt * 16 + n16] = __float2bfloat16(acc[mt][nt][r] + bias);
            }
    }
}

// ---------------- K2: relative logit row-vectors Rx, Ry ----------------
__global__ __launch_bounds__(256) void rel_kernel(
    const __hip_bfloat16* __restrict__ qbf,
    const float* __restrict__ kr_x, const float* __restrict__ kr_y,
    float* __restrict__ rx, float* __restrict__ ry)
{
    int g = blockIdx.x * 256 + threadIdx.x;
    int m = g & 63;
    int i = (g >> 6) & 1023;
    int bh = g >> 16;
    int yi = i >> 5, xi = i & 31;

    const __hip_bfloat16* qrow;
    const float* kr;
    float* dst;
    if (m < 32) {
        qrow = qbf + ((size_t)bh * HWP + i) * 32;
        kr = kr_x + (m - xi + 31) * 32;
        dst = rx + ((size_t)bh * HWP + i) * 32 + m;
    } else {
        int y2 = m - 32;
        qrow = qbf + ((size_t)bh * HWP + (xi * 32 + yi)) * 32;
        kr = kr_y + (y2 - xi + 31) * 32;
        dst = ry + ((size_t)bh * HWP + i) * 32 + y2;
    }
    float s = 0.f;
#pragma unroll
    for (int c = 0; c < 4; ++c) {
        s8v qa = *reinterpret_cast<const s8v*>(qrow + c * 8);
        const float* kp = kr + c * 8;
#pragma unroll
        for (int j = 0; j < 8; ++j) s += bf2f(qa[j]) * kp[j];
    }
    *dst = s;
}

// ---------------- K3: MFMA flash attention (attc now bf16) ----------------
__global__ __launch_bounds__(256) void attn_kernel(
    const __hip_bfloat16* __restrict__ qbf, const __hip_bfloat16* __restrict__ kbf,
    const __hip_bfloat16* __restrict__ vtb,
    const float* __restrict__ rx, const float* __restrict__ ry,
    __hip_bfloat16* __restrict__ attc)
{
    __shared__ __align__(16) __hip_bfloat16 Pb[4][16][48];

    const int tid = threadIdx.x;
    const int wv = tid >> 6;
    const int lane = tid & 63;
    const int n16 = lane & 15;
    const int quad = lane >> 4;
    const int bh = blockIdx.y;
    const int i0 = (blockIdx.x * 4 + wv) * 16;

    const size_t qoff = ((size_t)bh * HWP + i0 + n16) * 32 + quad * 8;
    s8v aq = *reinterpret_cast<const s8v*>(qbf + qoff);

    float rx0[4], rx1[4];
#pragma unroll
    for (int r = 0; r < 4; ++r) {
        const float* rp = rx + ((size_t)bh * HWP + i0 + quad * 4 + r) * 32;
        rx0[r] = rp[n16];
        rx1[r] = rp[n16 + 16];
    }
    const float* ryrow[4];
#pragma unroll
    for (int r = 0; r < 4; ++r)
        ryrow[r] = ry + ((size_t)bh * HWP + i0 + quad * 4 + r) * 32;

    float mrun[4], lrun[4];
    f32x4 O0 = {0.f, 0.f, 0.f, 0.f}, O1 = {0.f, 0.f, 0.f, 0.f};
#pragma unroll
    for (int r = 0; r < 4; ++r) { mrun[r] = -INFINITY; lrun[r] = 0.f; }

    const __hip_bfloat16* kbase = kbf + (size_t)bh * HWP * 32;
    const __hip_bfloat16* vbase = vtb + (size_t)bh * 32 * HWP;

    for (int jt = 0; jt < 32; ++jt) {
        const int j0 = jt * 32;
        s8v bk0 = *reinterpret_cast<const s8v*>(kbase + ((size_t)(j0 + n16) * 32 + quad * 8));
        s8v bk1 = *reinterpret_cast<const s8v*>(kbase + ((size_t)(j0 + 16 + n16) * 32 + quad * 8));
        s8v bv0 = *reinterpret_cast<const s8v*>(vbase + ((size_t)n16 * HWP + j0 + quad * 8));
        s8v bv1 = *reinterpret_cast<const s8v*>(vbase + ((size_t)(n16 + 16) * HWP + j0 + quad * 8));

        f32x4 s0 = {0.f, 0.f, 0.f, 0.f}, s1 = {0.f, 0.f, 0.f, 0.f};
        s0 = __builtin_amdgcn_mfma_f32_16x16x32_bf16(aq, bk0, s0, 0, 0, 0);
        s1 = __builtin_amdgcn_mfma_f32_16x16x32_bf16(aq, bk1, s1, 0, 0, 0);

        float p0[4], p1[4], alpha[4];
#pragma unroll
        for (int r = 0; r < 4; ++r) {
            float ryv = ryrow[r][jt];
            float a = s0[r] + rx0[r] + ryv;
            float b = s1[r] + rx1[r] + ryv;
            p0[r] = a; p1[r] = b;
            float t = fmaxf(a, b);
            t = fmaxf(t, __shfl_xor(t, 1));
            t = fmaxf(t, __shfl_xor(t, 2));
            t = fmaxf(t, __shfl_xor(t, 4));
            t = fmaxf(t, __shfl_xor(t, 8));
            float mnew = fmaxf(mrun[r], t);
            alpha[r] = __expf(mrun[r] - mnew);
            mrun[r] = mnew;
        }
#pragma unroll
        for (int r = 0; r < 4; ++r) {
            float a = __expf(p0[r] - mrun[r]);
            float b = __expf(p1[r] - mrun[r]);
            p0[r] = a; p1[r] = b;
            float ts = a + b;
            ts += __shfl_xor(ts, 1);
            ts += __shfl_xor(ts, 2);
            ts += __shfl_xor(ts, 4);
            ts += __shfl_xor(ts, 8);
            lrun[r] = lrun[r] * alpha[r] + ts;
            O0[r] *= alpha[r];
            O1[r] *= alpha[r];
        }
#pragma unroll
        for (int r = 0; r < 4; ++r) {
            Pb[wv][quad * 4 + r][n16]      = __float2bfloat16(p0[r]);
            Pb[wv][quad * 4 + r][n16 + 16] = __float2bfloat16(p1[r]);
        }
        s8v pA = *reinterpret_cast<const s8v*>(&Pb[wv][n16][quad * 8]);
        O0 = __builtin_amdgcn_mfma_f32_16x16x32_bf16(pA, bv0, O0, 0, 0, 0);
        O1 = __builtin_amdgcn_mfma_f32_16x16x32_bf16(pA, bv1, O1, 0, 0, 0);
    }

    const int b = bh >> 3, h = bh & 7;
#pragma unroll
    for (int r = 0; r < 4; ++r) {
        int i = i0 + quad * 4 + r;
        int yi = i >> 5, xi = i & 31;
        float inv = 1.0f / lrun[r];
        __hip_bfloat16* op = attc + ((size_t)(b * 256 + h * 32 + yi) * 32 + xi) * 32;
        op[n16] = __float2bfloat16(O0[r] * inv);
        op[n16 + 16] = __float2bfloat16(O1[r] * inv);
    }
}

// ---------------- K4a: transpose attc[b][c][pix] -> attT[b][pix][c] ----------
// grid (16 pix-tiles, 4 b), block 256; tile 256c x 64pix
__global__ __launch_bounds__(256) void trans_att(
    const __hip_bfloat16* __restrict__ attc, __hip_bfloat16* __restrict__ attT)
{
    __shared__ __align__(16) __hip_bfloat16 Ls[64][264];  // [pix][c], 33792 B
    const int tid = threadIdx.x;
    const int p0 = blockIdx.x * 64;
    const int b = blockIdx.y;

#pragma unroll
    for (int pass = 0; pass < 8; ++pass) {
        int ch = pass * 32 + (tid >> 3);
        int pg = (tid & 7) * 8;
        s8v v = *reinterpret_cast<const s8v*>(
            attc + ((size_t)(b * 256 + ch) * HWP) + p0 + pg);
#pragma unroll
        for (int j = 0; j < 8; ++j)
            Ls[pg + j][ch] = ((const __hip_bfloat16*)&v)[j];
    }
    __syncthreads();

    const int pix = tid >> 2;
    const int cb = (tid & 3) * 64;
    __hip_bfloat16* op = attT + ((size_t)(b * HWP + p0 + pix)) * 256 + cb;
#pragma unroll
    for (int g = 0; g < 8; ++g) {
        s8v v = *reinterpret_cast<const s8v*>(&Ls[pix][cb + g * 8]);
        *reinterpret_cast<s8v*>(op + g * 8) = v;
    }
}

// ---------------- K4b: 1x1 conv as MFMA GEMM, no LDS ----------------
// O[o][pix] = Wab[o][c] . attT[pix][c]; grid (4 o-tiles, 16 pix-tiles, 4 b)
__global__ __launch_bounds__(256) void conv1x1_gemm(
    const __hip_bfloat16* __restrict__ Wab, const __hip_bfloat16* __restrict__ attT,
    const float* __restrict__ att_b, float* __restrict__ out)
{
    const int tid = threadIdx.x;
    const int wv = tid >> 6;
    const int lane = tid & 63;
    const int n16 = lane & 15;
    const int quad = lane >> 4;
    const int o0 = blockIdx.x * 64;
    const int p0 = blockIdx.y * 64;
    const int b = blockIdx.z;
    const int oW = o0 + (wv >> 1) * 32;
    const int pW = p0 + (wv & 1) * 32;

    f32x4 acc[2][2];
#pragma unroll
    for (int i = 0; i < 2; ++i)
#pragma unroll
        for (int j = 0; j < 2; ++j) acc[i][j] = (f32x4){0.f, 0.f, 0.f, 0.f};

#pragma unroll
    for (int ks = 0; ks < 8; ++ks) {
        const int c0 = ks * 32 + quad * 8;
        s8v a0 = *reinterpret_cast<const s8v*>(Wab + (size_t)(oW + n16) * 256 + c0);
        s8v a1 = *reinterpret_cast<const s8v*>(Wab + (size_t)(oW + 16 + n16) * 256 + c0);
        s8v b0 = *reinterpret_cast<const s8v*>(attT + ((size_t)(b * HWP + pW + n16)) * 256 + c0);
        s8v b1 = *reinterpret_cast<const s8v*>(attT + ((size_t)(b * HWP + pW + 16 + n16)) * 256 + c0);
        acc[0][0] = __builtin_amdgcn_mfma_f32_16x16x32_bf16(a0, b0, acc[0][0], 0, 0, 0);
        acc[0][1] = __builtin_amdgcn_mfma_f32_16x16x32_bf16(a0, b1, acc[0][1], 0, 0, 0);
        acc[1][0] = __builtin_amdgcn_mfma_f32_16x16x32_bf16(a1, b0, acc[1][0], 0, 0, 0);
        acc[1][1] = __builtin_amdgcn_mfma_f32_16x16x32_bf16(a1, b1, acc[1][1], 0, 0, 0);
    }

#pragma unroll
    for (int mt = 0; mt < 2; ++mt)
#pragma unroll
        for (int r = 0; r < 4; ++r) {
            int o = oW + mt * 16 + quad * 4 + r;
            float bias = att_b[o];
            float* op = out + ((size_t)(b * 512 + 256 + o)) * HWP;
#pragma unroll
            for (int nt = 0; nt < 2; ++nt)
                op[pW + nt * 16 + n16] = acc[mt][nt][r] + bias;
        }
}

extern "C" void kernel_launch(void* const* d_in, const int* in_sizes, int n_in,
                              void* d_out, int out_size, void* d_ws, size_t ws_size,
                              hipStream_t stream) {
    const float* x      = (const float*)d_in[0];
    const float* conv_w = (const float*)d_in[1];
    const float* conv_b = (const float*)d_in[2];
    const float* qkv_w  = (const float*)d_in[3];
    const float* qkv_b  = (const float*)d_in[4];
    const float* att_w  = (const float*)d_in[5];
    const float* att_b  = (const float*)d_in[6];
    const float* kr_x   = (const float*)d_in[7];
    const float* kr_y   = (const float*)d_in[8];
    float* out = (float*)d_out;

    char* base = (char*)d_ws;
    const size_t MB = 1u << 20;
    float* rxb = (float*)(base + 0);
    float* ryb = (float*)(base + 4 * MB);
    __hip_bfloat16* qbf  = (__hip_bfloat16*)(base + 8 * MB);
    __hip_bfloat16* kbf  = (__hip_bfloat16*)(base + 10 * MB);
    __hip_bfloat16* vtb  = (__hip_bfloat16*)(base + 12 * MB);
    __hip_bfloat16* xT   = (__hip_bfloat16*)(base + 14 * MB);
    __hip_bfloat16* Wb   = (__hip_bfloat16*)(base + 16 * MB);
    __hip_bfloat16* attc = (__hip_bfloat16*)(base + 19 * MB);
    __hip_bfloat16* attT = (__hip_bfloat16*)(base + 21 * MB);
    __hip_bfloat16* Wab  = (__hip_bfloat16*)(base + 23 * MB);

    prep_xT<<<dim3(34, 4), 256, 0, stream>>>(x, xT);
    prep_w<<<dim3(4608), 256, 0, stream>>>(conv_w, qkv_w, Wb);
    prep_aw<<<dim3(256), 256, 0, stream>>>(att_w, Wab);
    conv_gemm<<<dim3(8, 8, 4), 256, 0, stream>>>(
        Wb, xT, conv_b, qkv_b, out, qbf, kbf, vtb);
    rel_kernel<<<dim3(8192), 256, 0, stream>>>(qbf, kr_x, kr_y, rxb, ryb);
    attn_kernel<<<dim3(16, 32), 256, 0, stream>>>(qbf, kbf, vtb, rxb, ryb, attc);
    trans_att<<<dim3(16, 4), 256, 0, stream>>>(attc, attT);
    conv1x1_gemm<<<dim3(4, 16, 4), 256, 0, stream>>>(Wab, attT, att_b, out);
}

// Round 5
// 194.616 us; speedup vs baseline: 5.4986x; 1.1214x over previous
//
#include <hip/hip_runtime.h>
#include <hip/hip_bf16.h>
#include <math.h>

#define BN 4
#define CIN 128
#define HH 32
#define WW 32
#define HWP 1024
#define NHEAD 8

typedef __attribute__((ext_vector_type(8))) short s8v;
typedef __attribute__((ext_vector_type(4))) float f32x4;

__device__ __forceinline__ float bf2f(short h) {
    union { unsigned u; float f; } v;
    v.u = ((unsigned)(unsigned short)h) << 16;
    return v.f;
}

// ---------------- P1: x (NCHW fp32) -> xT[b][34][34][128] bf16, zero halo ----
__global__ __launch_bounds__(256) void prep_xT(
    const float* __restrict__ x, __hip_bfloat16* __restrict__ xT)
{
    __shared__ float xs[CIN][33];
    const int yy = blockIdx.x;
    const int b = blockIdx.y;
    const int tid = threadIdx.x;
    const bool inner = (yy >= 1 && yy <= 32);

    if (inner) {
        for (int idx = tid; idx < CIN * 32; idx += 256) {
            int ci = idx >> 5, xx = idx & 31;
            xs[ci][xx] = x[((size_t)(b * CIN + ci) * HH + (yy - 1)) * WW + xx];
        }
    }
    __syncthreads();

    for (int idx = tid; idx < 34 * 128; idx += 256) {
        int xx = idx >> 7, ci = idx & 127;
        float v = 0.f;
        if (inner && xx >= 1 && xx <= 32) v = xs[ci][xx - 1];
        xT[((size_t)(b * 34 + yy) * 34 + xx) * 128 + ci] = __float2bfloat16(v);
    }
}

// ---------------- P2: weights -> Wb[1024][1152] bf16, K order (ky,kx,ci) ----
__global__ __launch_bounds__(256) void prep_w(
    const float* __restrict__ conv_w, const float* __restrict__ qkv_w,
    __hip_bfloat16* __restrict__ Wb)
{
    int g = blockIdx.x * 256 + threadIdx.x;    // 1024*1152
    int co = g / 1152;
    int k = g - co * 1152;
    int kk = k >> 7, ci = k & 127;             // kk = ky*3+kx
    float v;
    if (co < 256) v = conv_w[((size_t)(co * 128 + ci) * 9) + kk];
    else          v = qkv_w[((size_t)((co - 256) * 128 + ci) * 9) + kk];
    Wb[(size_t)co * 1152 + k] = __float2bfloat16(v);
}

// ---------------- P3: att_w fp32 -> bf16 ----------------
__global__ __launch_bounds__(256) void prep_aw(
    const float* __restrict__ att_w, __hip_bfloat16* __restrict__ Wab)
{
    int g = blockIdx.x * 256 + threadIdx.x;    // 65536
    Wab[g] = __float2bfloat16(att_w[g]);
}

// ---------------- K1: MFMA implicit-GEMM 3x3 conv ----------------
// BK=128 (one (ky,kx) plane / step, 9 steps), register-prefetch pipeline,
// XOR-swizzled LDS (stride 128, 64 KB total, 2-way-max bank pattern).
__global__ __launch_bounds__(256) void conv_gemm(
    const __hip_bfloat16* __restrict__ Wb, const __hip_bfloat16* __restrict__ xT,
    const float* __restrict__ conv_b, const float* __restrict__ qkv_b,
    float* __restrict__ out,
    __hip_bfloat16* __restrict__ qbf, __hip_bfloat16* __restrict__ kbf,
    __hip_bfloat16* __restrict__ vtb)
{
    __shared__ __align__(16) __hip_bfloat16 As[128 * 128];  // 32 KB
    __shared__ __align__(16) __hip_bfloat16 Bs[128 * 128];  // 32 KB

    const int tid = threadIdx.x;
    const int wv = tid >> 6;
    const int lane = tid & 63;
    const int n16 = lane & 15;
    const int quad = lane >> 4;
    const int co0 = blockIdx.x * 128;
    const int y0 = blockIdx.y * 4;
    const int b = blockIdx.z;
    const int mh = wv >> 1, nh = wv & 1;

    // staging geometry: thread covers rows (tid>>4)+16i, chunk h = tid&15
    const int rbase = tid >> 4;       // 0..15
    const int hh = tid & 15;          // chunk-of-8 index
    const int swz = (hh ^ rbase) * 8; // XOR swizzle (row&15 == rbase for all i)
    const __hip_bfloat16* aGbase = Wb + (size_t)(co0 + rbase) * 1152 + hh * 8;

    f32x4 acc[4][4];
#pragma unroll
    for (int i = 0; i < 4; ++i)
#pragma unroll
        for (int j = 0; j < 4; ++j) acc[i][j] = (f32x4){0.f, 0.f, 0.f, 0.f};

    s8v ra[8], rb[8];

    // ---- load tile for step kk into registers
    auto load_tile = [&](int kk, s8v* la, s8v* lb) {
        const int ky = kk / 3, kx = kk - ky * 3;
#pragma unroll
        for (int i = 0; i < 8; ++i)
            la[i] = *reinterpret_cast<const s8v*>(aGbase + (size_t)(16 * i) * 1152 + kk * 128);
#pragma unroll
        for (int i = 0; i < 8; ++i) {
            int p = rbase + 16 * i;
            int row = y0 + (p >> 5) + ky;
            int xx = (p & 31) + kx;
            lb[i] = *reinterpret_cast<const s8v*>(
                xT + ((size_t)(b * 34 + row) * 34 + xx) * 128 + hh * 8);
        }
    };

    load_tile(0, ra, rb);

    for (int s = 0; s < 9; ++s) {
        __syncthreads();   // previous step's LDS reads done
#pragma unroll
        for (int i = 0; i < 8; ++i) {
            *reinterpret_cast<s8v*>(&As[(rbase + 16 * i) * 128 + swz]) = ra[i];
            *reinterpret_cast<s8v*>(&Bs[(rbase + 16 * i) * 128 + swz]) = rb[i];
        }
        __syncthreads();
        if (s < 8) load_tile(s + 1, ra, rb);   // in flight during compute

#pragma unroll
        for (int ksub = 0; ksub < 4; ++ksub) {
            const int chunk = ((ksub * 4 + quad) ^ n16) * 8;
            s8v af[4], bfr[4];
#pragma unroll
            for (int mt = 0; mt < 4; ++mt)
                af[mt] = *reinterpret_cast<const s8v*>(&As[(mh * 64 + mt * 16 + n16) * 128 + chunk]);
#pragma unroll
            for (int nt = 0; nt < 4; ++nt)
                bfr[nt] = *reinterpret_cast<const s8v*>(&Bs[(nh * 64 + nt * 16 + n16) * 128 + chunk]);
#pragma unroll
            for (int mt = 0; mt < 4; ++mt)
#pragma unroll
                for (int nt = 0; nt < 4; ++nt)
                    acc[mt][nt] = __builtin_amdgcn_mfma_f32_16x16x32_bf16(af[mt], bfr[nt], acc[mt][nt], 0, 0, 0);
        }
    }

    const int coBase = co0 + mh * 64;
    const int pixBase = y0 * 32 + nh * 64;
    const int seg = coBase >> 8;

    if (seg == 0) {
#pragma unroll
        for (int mt = 0; mt < 4; ++mt)
#pragma unroll
            for (int r = 0; r < 4; ++r) {
                int co = coBase + mt * 16 + quad * 4 + r;
                float bias = conv_b[co];
                float* op = out + (size_t)(b * 512 + co) * HWP + pixBase;
#pragma unroll
                for (int nt = 0; nt < 4; ++nt)
                    op[nt * 16 + n16] = acc[mt][nt][r] + bias;
            }
    } else if (seg == 1) {
        const float scale = 0.17677669529663687f;
#pragma unroll
        for (int mt = 0; mt < 4; ++mt)
#pragma unroll
            for (int r = 0; r < 4; ++r) {
                int c2 = coBase - 256 + mt * 16 + quad * 4 + r;
                float bias = qkv_b[c2];
                int h = c2 >> 5, d = c2 & 31;
                int bh = b * NHEAD + h;
#pragma unroll
                for (int nt = 0; nt < 4; ++nt) {
                    int pix = pixBase + nt * 16 + n16;
                    qbf[((size_t)bh * HWP + pix) * 32 + d] =
                        __float2bfloat16((acc[mt][nt][r] + bias) * scale);
                }
            }
    } else if (seg == 2) {
#pragma unroll
        for (int mt = 0; mt < 4; ++mt)
#pragma unroll
            for (int r = 0; r < 4; ++r) {
                int c2 = coBase - 512 + mt * 16 + quad * 4 + r;
                float bias = qkv_b[c2 + 256];
                int h = c2 >> 5, d = c2 & 31;
                int bh = b * NHEAD + h;
#pragma unroll
                for (int nt = 0; nt < 4; ++nt) {
                    int pix = pixBase + nt * 16 + n16;
                    kbf[((size_t)bh * HWP + pix) * 32 + d] =
                        __float2bfloat16(acc[mt][nt][r] + bias);
                }
            }
    } else {
#pragma unroll
        for (int mt = 0; mt < 4; ++mt)
#pragma unroll
            for (int r = 0; r < 4; ++r) {
                int c2 = coBase - 768 + mt * 16 + quad * 4 + r;
                float bias = qkv_b[c2 + 512];
                int h = c2 >> 5, d = c2 & 31;
                int bh = b * NHEAD + h;
                __hip_bfloat16* vp = vtb + ((size_t)bh * 32 + d) * HWP + pixBase;
#pragma unroll
                for (int nt = 0; nt < 4; ++nt)
                    vp[nt * 16 + n16] = __float2bfloat16(acc[mt][nt][r] + bias);
            }
    }
}

// ---------------- K2: relative logit row-vectors Rx, Ry ----------------
__global__ __launch_bounds__(256) void rel_kernel(
    const __hip_bfloat16* __restrict__ qbf,
    const float* __restrict__ kr_x, const float* __restrict__ kr_y,
    float* __restrict__ rx, float* __restrict__ ry)
{
    int g = blockIdx.x * 256 + threadIdx.x;
    int m = g & 63;
    int i = (g >> 6) & 1023;
    int bh = g >> 16;
    int yi = i >> 5, xi = i & 31;

    const __hip_bfloat16* qrow;
    const float* kr;
    float* dst;
    if (m < 32) {
        qrow = qbf + ((size_t)bh * HWP + i) * 32;
        kr = kr_x + (m - xi + 31) * 32;
        dst = rx + ((size_t)bh * HWP + i) * 32 + m;
    } else {
        int y2 = m - 32;
        qrow = qbf + ((size_t)bh * HWP + (xi * 32 + yi)) * 32;
        kr = kr_y + (y2 - xi + 31) * 32;
        dst = ry + ((size_t)bh * HWP + i) * 32 + y2;
    }
    float s = 0.f;
#pragma unroll
    for (int c = 0; c < 4; ++c) {
        s8v qa = *reinterpret_cast<const s8v*>(qrow + c * 8);
        const float* kp = kr + c * 8;
#pragma unroll
        for (int j = 0; j < 8; ++j) s += bf2f(qa[j]) * kp[j];
    }
    *dst = s;
}

// ---------------- K3: MFMA flash attention ----------------
__global__ __launch_bounds__(256) void attn_kernel(
    const __hip_bfloat16* __restrict__ qbf, const __hip_bfloat16* __restrict__ kbf,
    const __hip_bfloat16* __restrict__ vtb,
    const float* __restrict__ rx, const float* __restrict__ ry,
    __hip_bfloat16* __restrict__ attc)
{
    __shared__ __align__(16) __hip_bfloat16 Pb[4][16][48];

    const int tid = threadIdx.x;
    const int wv = tid >> 6;
    const int lane = tid & 63;
    const int n16 = lane & 15;
    const int quad = lane >> 4;
    const int bh = blockIdx.y;
    const int i0 = (blockIdx.x * 4 + wv) * 16;

    const size_t qoff = ((size_t)bh * HWP + i0 + n16) * 32 + quad * 8;
    s8v aq = *reinterpret_cast<const s8v*>(qbf + qoff);

    float rx0[4], rx1[4];
#pragma unroll
    for (int r = 0; r < 4; ++r) {
        const float* rp = rx + ((size_t)bh * HWP + i0 + quad * 4 + r) * 32;
        rx0[r] = rp[n16];
        rx1[r] = rp[n16 + 16];
    }
    const float* ryrow[4];
#pragma unroll
    for (int r = 0; r < 4; ++r)
        ryrow[r] = ry + ((size_t)bh * HWP + i0 + quad * 4 + r) * 32;

    float mrun[4], lrun[4];
    f32x4 O0 = {0.f, 0.f, 0.f, 0.f}, O1 = {0.f, 0.f, 0.f, 0.f};
#pragma unroll
    for (int r = 0; r < 4; ++r) { mrun[r] = -INFINITY; lrun[r] = 0.f; }

    const __hip_bfloat16* kbase = kbf + (size_t)bh * HWP * 32;
    const __hip_bfloat16* vbase = vtb + (size_t)bh * 32 * HWP;

    for (int jt = 0; jt < 32; ++jt) {
        const int j0 = jt * 32;
        s8v bk0 = *reinterpret_cast<const s8v*>(kbase + ((size_t)(j0 + n16) * 32 + quad * 8));
        s8v bk1 = *reinterpret_cast<const s8v*>(kbase + ((size_t)(j0 + 16 + n16) * 32 + quad * 8));
        s8v bv0 = *reinterpret_cast<const s8v*>(vbase + ((size_t)n16 * HWP + j0 + quad * 8));
        s8v bv1 = *reinterpret_cast<const s8v*>(vbase + ((size_t)(n16 + 16) * HWP + j0 + quad * 8));

        f32x4 s0 = {0.f, 0.f, 0.f, 0.f}, s1 = {0.f, 0.f, 0.f, 0.f};
        s0 = __builtin_amdgcn_mfma_f32_16x16x32_bf16(aq, bk0, s0, 0, 0, 0);
        s1 = __builtin_amdgcn_mfma_f32_16x16x32_bf16(aq, bk1, s1, 0, 0, 0);

        float p0[4], p1[4], alpha[4];
#pragma unroll
        for (int r = 0; r < 4; ++r) {
            float ryv = ryrow[r][jt];
            float a = s0[r] + rx0[r] + ryv;
            float b = s1[r] + rx1[r] + ryv;
            p0[r] = a; p1[r] = b;
            float t = fmaxf(a, b);
            t = fmaxf(t, __shfl_xor(t, 1));
            t = fmaxf(t, __shfl_xor(t, 2));
            t = fmaxf(t, __shfl_xor(t, 4));
            t = fmaxf(t, __shfl_xor(t, 8));
            float mnew = fmaxf(mrun[r], t);
            alpha[r] = __expf(mrun[r] - mnew);
            mrun[r] = mnew;
        }
#pragma unroll
        for (int r = 0; r < 4; ++r) {
            float a = __expf(p0[r] - mrun[r]);
            float b = __expf(p1[r] - mrun[r]);
            p0[r] = a; p1[r] = b;
            float ts = a + b;
            ts += __shfl_xor(ts, 1);
            ts += __shfl_xor(ts, 2);
            ts += __shfl_xor(ts, 4);
            ts += __shfl_xor(ts, 8);
            lrun[r] = lrun[r] * alpha[r] + ts;
            O0[r] *= alpha[r];
            O1[r] *= alpha[r];
        }
#pragma unroll
        for (int r = 0; r < 4; ++r) {
            Pb[wv][quad * 4 + r][n16]      = __float2bfloat16(p0[r]);
            Pb[wv][quad * 4 + r][n16 + 16] = __float2bfloat16(p1[r]);
        }
        s8v pA = *reinterpret_cast<const s8v*>(&Pb[wv][n16][quad * 8]);
        O0 = __builtin_amdgcn_mfma_f32_16x16x32_bf16(pA, bv0, O0, 0, 0, 0);
        O1 = __builtin_amdgcn_mfma_f32_16x16x32_bf16(pA, bv1, O1, 0, 0, 0);
    }

    const int b = bh >> 3, h = bh & 7;
#pragma unroll
    for (int r = 0; r < 4; ++r) {
        int i = i0 + quad * 4 + r;
        int yi = i >> 5, xi = i & 31;
        float inv = 1.0f / lrun[r];
        __hip_bfloat16* op = attc + ((size_t)(b * 256 + h * 32 + yi) * 32 + xi) * 32;
        op[n16] = __float2bfloat16(O0[r] * inv);
        op[n16 + 16] = __float2bfloat16(O1[r] * inv);
    }
}

// ---------------- K4a: transpose attc[b][c][pix] -> attT[b][pix][c] ----------
__global__ __launch_bounds__(256) void trans_att(
    const __hip_bfloat16* __restrict__ attc, __hip_bfloat16* __restrict__ attT)
{
    __shared__ __align__(16) __hip_bfloat16 Ls[64][264];
    const int tid = threadIdx.x;
    const int p0 = blockIdx.x * 64;
    const int b = blockIdx.y;

#pragma unroll
    for (int pass = 0; pass < 8; ++pass) {
        int ch = pass * 32 + (tid >> 3);
        int pg = (tid & 7) * 8;
        s8v v = *reinterpret_cast<const s8v*>(
            attc + ((size_t)(b * 256 + ch) * HWP) + p0 + pg);
#pragma unroll
        for (int j = 0; j < 8; ++j)
            Ls[pg + j][ch] = ((const __hip_bfloat16*)&v)[j];
    }
    __syncthreads();

    const int pix = tid >> 2;
    const int cb = (tid & 3) * 64;
    __hip_bfloat16* op = attT + ((size_t)(b * HWP + p0 + pix)) * 256 + cb;
#pragma unroll
    for (int g = 0; g < 8; ++g) {
        s8v v = *reinterpret_cast<const s8v*>(&Ls[pix][cb + g * 8]);
        *reinterpret_cast<s8v*>(op + g * 8) = v;
    }
}

// ---------------- K4b: 1x1 conv as MFMA GEMM, no LDS ----------------
__global__ __launch_bounds__(256) void conv1x1_gemm(
    const __hip_bfloat16* __restrict__ Wab, const __hip_bfloat16* __restrict__ attT,
    const float* __restrict__ att_b, float* __restrict__ out)
{
    const int tid = threadIdx.x;
    const int wv = tid >> 6;
    const int lane = tid & 63;
    const int n16 = lane & 15;
    const int quad = lane >> 4;
    const int o0 = blockIdx.x * 64;
    const int p0 = blockIdx.y * 64;
    const int b = blockIdx.z;
    const int oW = o0 + (wv >> 1) * 32;
    const int pW = p0 + (wv & 1) * 32;

    f32x4 acc[2][2];
#pragma unroll
    for (int i = 0; i < 2; ++i)
#pragma unroll
        for (int j = 0; j < 2; ++j) acc[i][j] = (f32x4){0.f, 0.f, 0.f, 0.f};

#pragma unroll
    for (int ks = 0; ks < 8; ++ks) {
        const int c0 = ks * 32 + quad * 8;
        s8v a0 = *reinterpret_cast<const s8v*>(Wab + (size_t)(oW + n16) * 256 + c0);
        s8v a1 = *reinterpret_cast<const s8v*>(Wab + (size_t)(oW + 16 + n16) * 256 + c0);
        s8v b0 = *reinterpret_cast<const s8v*>(attT + ((size_t)(b * HWP + pW + n16)) * 256 + c0);
        s8v b1 = *reinterpret_cast<const s8v*>(attT + ((size_t)(b * HWP + pW + 16 + n16)) * 256 + c0);
        acc[0][0] = __builtin_amdgcn_mfma_f32_16x16x32_bf16(a0, b0, acc[0][0], 0, 0, 0);
        acc[0][1] = __builtin_amdgcn_mfma_f32_16x16x32_bf16(a0, b1, acc[0][1], 0, 0, 0);
        acc[1][0] = __builtin_amdgcn_mfma_f32_16x16x32_bf16(a1, b0, acc[1][0], 0, 0, 0);
        acc[1][1] = __builtin_amdgcn_mfma_f32_16x16x32_bf16(a1, b1, acc[1][1], 0, 0, 0);
    }

#pragma unroll
    for (int mt = 0; mt < 2; ++mt)
#pragma unroll
        for (int r = 0; r < 4; ++r) {
            int o = oW + mt * 16 + quad * 4 + r;
            float bias = att_b[o];
            float* op = out + ((size_t)(b * 512 + 256 + o)) * HWP;
#pragma unroll
            for (int nt = 0; nt < 2; ++nt)
                op[pW + nt * 16 + n16] = acc[mt][nt][r] + bias;
        }
}

extern "C" void kernel_launch(void* const* d_in, const int* in_sizes, int n_in,
                              void* d_out, int out_size, void* d_ws, size_t ws_size,
                              hipStream_t stream) {
    const float* x      = (const float*)d_in[0];
    const float* conv_w = (const float*)d_in[1];
    const float* conv_b = (const float*)d_in[2];
    const float* qkv_w  = (const float*)d_in[3];
    const float* qkv_b  = (const float*)d_in[4];
    const float* att_w  = (const float*)d_in[5];
    const float* att_b  = (const float*)d_in[6];
    const float* kr_x   = (const float*)d_in[7];
    const float* kr_y   = (const float*)d_in[8];
    float* out = (float*)d_out;

    char* base = (char*)d_ws;
    const size_t MB = 1u << 20;
    float* rxb = (float*)(base + 0);
    float* ryb = (float*)(base + 4 * MB);
    __hip_bfloat16* qbf  = (__hip_bfloat16*)(base + 8 * MB);
    __hip_bfloat16* kbf  = (__hip_bfloat16*)(base + 10 * MB);
    __hip_bfloat16* vtb  = (__hip_bfloat16*)(base + 12 * MB);
    __hip_bfloat16* xT   = (__hip_bfloat16*)(base + 14 * MB);
    __hip_bfloat16* Wb   = (__hip_bfloat16*)(base + 16 * MB);
    __hip_bfloat16* attc = (__hip_bfloat16*)(base + 19 * MB);
    __hip_bfloat16* attT = (__hip_bfloat16*)(base + 21 * MB);
    __hip_bfloat16* Wab  = (__hip_bfloat16*)(base + 23 * MB);

    prep_xT<<<dim3(34, 4), 256, 0, stream>>>(x, xT);
    prep_w<<<dim3(4608), 256, 0, stream>>>(conv_w, qkv_w, Wb);
    prep_aw<<<dim3(256), 256, 0, stream>>>(att_w, Wab);
    conv_gemm<<<dim3(8, 8, 4), 256, 0, stream>>>(
        Wb, xT, conv_b, qkv_b, out, qbf, kbf, vtb);
    rel_kernel<<<dim3(8192), 256, 0, stream>>>(qbf, kr_x, kr_y, rxb, ryb);
    attn_kernel<<<dim3(16, 32), 256, 0, stream>>>(qbf, kbf, vtb, rxb, ryb, attc);
    trans_att<<<dim3(16, 4), 256, 0, stream>>>(attc, attT);
    conv1x1_gemm<<<dim3(4, 16, 4), 256, 0, stream>>>(Wab, attT, att_b, out);
}